// Round 12
// baseline (354.850 us; speedup 1.0000x reference)
//
#include <hip/hip_runtime.h>
#include <math.h>

// ===========================================================================
// RAVE noise generator.
//  x:[16][512][4096] w1,w2:[512][512][3] w3:[10][512][3] noise:[16][512][2][8]
//  out:[16][2][4096]
//
// Fast path (split-bf16 MFMA):
//   prep_w:  w -> Wf frag-order split-bf16 (MFMA B-operand layout)
//   conv1_fused: x (fp32, reg-staged + in-kernel transpose/split) -> h1p
//   conv_mfma (conv2): h1p -> h2t fp32 t-major [b][1026][512], leaky
//   conv3_tmaj: fused conv3 + mod_sigmoid + IR + causal FIR + transpose
// Round-12: t-widened tiles. Wave = 128t x 64co (acc[4][2]), block =
// 128t x 256co, 4 waves / 256 threads. B-frag bytes per MFMA HALVE (R10
// falsification showed B-traffic-per-MFMA is the operative knob: halving
// wave-t doubled B traffic and cost 33%). LDS 2x258x128B = 66KB (>64KB
// static OK on gfx950, cf. m201's 128KB), 2 blocks/CU -> occupancy
// unchanged at 8 waves/CU, isolating tile efficiency from occupancy.
// ===========================================================================

typedef __attribute__((ext_vector_type(8)))  short bf16x8;
typedef __attribute__((ext_vector_type(16))) float f32x16;

__device__ __forceinline__ unsigned short f2bf_rne(float f) {
    unsigned int u = __float_as_uint(f);
    unsigned int r = u + 0x7fff + ((u >> 16) & 1);
    return (unsigned short)(r >> 16);
}
__device__ __forceinline__ float bf2f(unsigned short h) {
    return __uint_as_float(((unsigned int)h) << 16);
}
__device__ __forceinline__ void gload_lds16(const void* g, void* l) {
    __builtin_amdgcn_global_load_lds(
        (const __attribute__((address_space(1))) unsigned int*)g,
        (__attribute__((address_space(3))) unsigned int*)l, 16, 0, 0);
}
__device__ __forceinline__ int swz1(int r) {        // conv1_fused swizzle
    return ((r >> 1) ^ (r >> 4)) & 7;
}

// ---------------------------------------------------------------------------
// prep_w: w[co][ci][3] fp32 -> frag-order split-bf16.
// frag f = (((cb*16 + cob)*3 + tap)*2 + hl)*2 + ks ; 1 KB per frag;
// lane l holds B[ci = cb*32 + ks*16 + (l>>5)*8 + j][co = cob*32 + (l&31)].
// ---------------------------------------------------------------------------
__global__ void prep_w_kernel(const float* __restrict__ W, short* __restrict__ Wf)
{
    int gid = blockIdx.x * 256 + threadIdx.x;   // 0..196607
    int f = gid >> 6, l = gid & 63;
    int ks = f & 1, hl = (f >> 1) & 1;
    int k  = (f >> 2) % 3;
    int rem = (f >> 2) / 3;
    int cob = rem & 15, cb = rem >> 4;
    int co  = cob * 32 + (l & 31);
    int ci0 = cb * 32 + ks * 16 + (l >> 5) * 8;
    bf16x8 o;
#pragma unroll
    for (int j = 0; j < 8; ++j) {
        float v = W[((size_t)co * 512 + ci0 + j) * 3 + k];
        unsigned short hi = f2bf_rne(v);
        o[j] = hl ? (short)f2bf_rne(v - bf2f(hi)) : (short)hi;
    }
    *(bf16x8*)((char*)Wf + (size_t)f * 1024 + l * 16) = o;
}

// zero pad rows: h1p rows 2048-2049 (4KB/b) + h2t rows 1024-1025 (4KB/b)
__global__ void zero_pads(char* __restrict__ h1p, char* __restrict__ h2t) {
    int id = blockIdx.x * 256 + threadIdx.x;    // 32768 threads
    if (id < 16384) {
        int b = id >> 10, w = id & 1023;
        *(float*)(h1p + ((size_t)b * 2080 + 2048) * 2048 + (size_t)w * 4) = 0.f;
    } else {
        int id2 = id - 16384;
        int b = id2 >> 10, w = id2 & 1023;
        *(float*)(h2t + ((size_t)b * 1026 + 1024) * 2048 + (size_t)w * 4) = 0.f;
    }
}

// ---------------------------------------------------------------------------
// conv1_fused: stride-2 k=3 conv as implicit GEMM, split-bf16, 32x32x16 MFMA,
// reading x (fp32 [b][ci][t]) DIRECTLY. Block = 128t x 256co, 4 waves;
// wave = 128t x 64co (acc[4][2]). Per K-step (32 ci): issue x float4 loads
// for tile cb+1; 6 MFMA phases (per-phase B frags from L2, reused over
// 4 tp); convert fp32->split-bf16 (trunc hi) into other buffer; barrier.
// ---------------------------------------------------------------------------
__global__ __launch_bounds__(256, 2) void conv1_fused(
    const float* __restrict__ X, const short* __restrict__ Wf,
    const float* __restrict__ Bias, char* __restrict__ Out)
{
    __shared__ char AB[2][33024];   // 258 rows x 128 B, double-buffered

    const int tid = threadIdx.x;
    const int l   = tid & 63;
    const int wid = tid >> 6;
    const int tl0 = l & 31;
    const int lh  = l >> 5;

    // block swizzle: pair the 2 co-tiles of a (b, t-tile) on the same XCD
    int p = blockIdx.x;             // 512 blocks
    int chunk = p >> 5, slot = p & 31;
    int gl = slot & 15, c = slot >> 4;
    int g = chunk * 16 + gl;        // 0..255
    int zb = g >> 4, y = g & 15;    // Yt = 16 for conv1

    const int bt0 = y * 128;
    const int r0  = 2 * bt0;
    const float* Xb = X + (size_t)zb * 512 * 4096;

    // staging thread mapping: 16 row-groups x 16 rows, 16 ci-pairs
    const int rg   = tid & 15;            // rows rg*16 .. rg*16+15
    const int cip  = tid >> 4;            // ci = 2*cip, 2*cip+1
    const int ci   = 2 * cip;
    const int u_hi = ci >> 3;             // 0..3
    const int u_lo = 4 + u_hi;
    const int coff = (ci & 7) * 2;        // 0,4,8,12 (4B aligned)

    f32x16 acc[4][2];
#pragma unroll
    for (int tp = 0; tp < 4; ++tp)
#pragma unroll
        for (int cp = 0; cp < 2; ++cp) acc[tp][cp] = (f32x16)(0.0f);

    const int cbase = c * 8 + wid * 2;    // co-unit base (32co units)

    float4 fa[4], fb[4];                  // staged rows (2 ci x 16 rows)
    float  fextra = 0.f;                  // row 256 (tid<32 only)

    auto issue_loads = [&](int cb) {
        const float* s0 = Xb + (size_t)(cb * 32 + ci) * 4096 + r0 + rg * 16;
#pragma unroll
        for (int i = 0; i < 4; ++i) {
            fa[i] = *(const float4*)(s0 + i * 4);
            fb[i] = *(const float4*)(s0 + 4096 + i * 4);
        }
        if (tid < 32) {
            int rr = r0 + 256;
            fextra = (rr < 4096) ? Xb[(size_t)(cb * 32 + tid) * 4096 + rr] : 0.f;
        }
    };

    auto write_k = [&](char* buf, int r, float a, float b) {
        int sw = swz1(r);
        unsigned int ua = __float_as_uint(a);
        unsigned int ub = __float_as_uint(b);
        float ha = __uint_as_float(ua & 0xffff0000u);   // trunc hi
        float hb = __uint_as_float(ub & 0xffff0000u);
        unsigned short la = f2bf_rne(a - ha);            // exact residual
        unsigned short lb = f2bf_rne(b - hb);
        *(unsigned int*)(buf + r * 128 + ((u_hi ^ sw) << 4) + coff) =
            (ua >> 16) | (ub & 0xffff0000u);
        *(unsigned int*)(buf + r * 128 + ((u_lo ^ sw) << 4) + coff) =
            (unsigned int)la | ((unsigned int)lb << 16);
    };
    auto write_tile = [&](char* buf) {
#pragma unroll
        for (int i = 0; i < 4; ++i) {
            int rb = rg * 16 + i * 4;
            write_k(buf, rb + 0, fa[i].x, fb[i].x);
            write_k(buf, rb + 1, fa[i].y, fb[i].y);
            write_k(buf, rb + 2, fa[i].z, fb[i].z);
            write_k(buf, rb + 3, fa[i].w, fb[i].w);
        }
        if (tid < 32) {
            int sw = swz1(256);
            unsigned int ue = __float_as_uint(fextra);
            float he = __uint_as_float(ue & 0xffff0000u);
            unsigned short lo = f2bf_rne(fextra - he);
            int uh = (tid >> 3) ^ sw;
            int ul = (4 + (tid >> 3)) ^ sw;
            *(unsigned short*)(buf + 256 * 128 + (uh << 4) + (tid & 7) * 2) =
                (unsigned short)(ue >> 16);
            *(unsigned short*)(buf + 256 * 128 + (ul << 4) + (tid & 7) * 2) = lo;
        }
    };

    // B-frag pointer: f = ((co_unit*3 + tap)*2 + hl)*2 + ks, 1 KB per frag
    auto wptr = [&](int cb_, int cp, int tap, int ks, int hl) -> const char* {
        size_t f0 = ((((size_t)(cb_ * 16 + cbase + cp) * 3 + tap) * 2 + hl) * 2 + ks);
        return (const char*)Wf + f0 * 1024 + (size_t)l * 16;
    };

    // prologue: tile 0 into AB[0]
    issue_loads(0);
    write_tile(AB[0]);
    __syncthreads();

    for (int cb = 0; cb < 16; ++cb) {
        if (cb < 15) issue_loads(cb + 1);
        const char* Ab = AB[cb & 1];
#pragma unroll
        for (int ph = 0; ph < 6; ++ph) {
            const int tap = ph >> 1, ks = ph & 1;
            bf16x8 a0[4], a1[4], bb[2][2];
#pragma unroll
            for (int tp = 0; tp < 4; ++tp) {
                int rl = 2 * (tp * 32 + tl0) + tap;
                int sw = swz1(rl);
                int qb = ks * 2 + lh;
                a0[tp] = *(const bf16x8*)(Ab + rl * 128 + ((qb ^ sw) << 4));
                a1[tp] = *(const bf16x8*)(Ab + rl * 128 + (((qb + 4) ^ sw) << 4));
            }
#pragma unroll
            for (int cp = 0; cp < 2; ++cp) {
                const char* wp = wptr(cb, cp, tap, ks, 0);
                bb[0][cp] = *(const bf16x8*)(wp);
                bb[1][cp] = *(const bf16x8*)(wp + 2048);   // hl=1 frag
            }
#pragma unroll
            for (int tp = 0; tp < 4; ++tp)
#pragma unroll
                for (int cp = 0; cp < 2; ++cp) {
                    acc[tp][cp] = __builtin_amdgcn_mfma_f32_32x32x16_bf16(
                        a0[tp], bb[0][cp], acc[tp][cp], 0, 0, 0);   // hi*hi
                    acc[tp][cp] = __builtin_amdgcn_mfma_f32_32x32x16_bf16(
                        a0[tp], bb[1][cp], acc[tp][cp], 0, 0, 0);   // hi*lo
                    acc[tp][cp] = __builtin_amdgcn_mfma_f32_32x32x16_bf16(
                        a1[tp], bb[0][cp], acc[tp][cp], 0, 0, 0);   // lo*hi
                }
        }
        if (cb < 15) write_tile((char*)AB[(cb + 1) & 1]);
        __syncthreads();
    }

    // ---- epilogue: bias + leaky, split-bf16 packed store to h1p (trunc hi)
    const size_t outB = (size_t)zb * 2080 * 2048;
    const int colb = c * 256 + wid * 64 + tl0;
#pragma unroll
    for (int cp = 0; cp < 2; ++cp) {
        int co = colb + cp * 32;
        float bv = Bias[co];
#pragma unroll
        for (int tp = 0; tp < 4; ++tp) {
            int trow = bt0 + tp * 32 + 4 * lh;
#pragma unroll
            for (int r = 0; r < 16; ++r) {
                int row = trow + (r & 3) + 8 * (r >> 2);
                float v = acc[tp][cp][r] + bv;
                v = v < 0.f ? 0.2f * v : v;
                char* po = Out + outB + (size_t)row * 2048;
                unsigned int uv = __float_as_uint(v);
                float hf = __uint_as_float(uv & 0xffff0000u);
                *(unsigned short*)(po + co * 2) = (unsigned short)(uv >> 16);
                *(unsigned short*)(po + 1024 + co * 2) = f2bf_rne(v - hf);
            }
        }
    }
}

// ---------------------------------------------------------------------------
// conv_mfma (conv2): gload_lds A staging from packed h1p. Block = 128t x
// 256co, 4 waves; wave = 128t x 64co. mode 1: fp32 t-major output (h2t).
// ---------------------------------------------------------------------------
#define CONV_UNITS2 2056   // 257 rows * 8 x 16B units

__global__ __launch_bounds__(256, 2) void conv_mfma(
    const char* __restrict__ Xp, const short* __restrict__ Wf,
    const float* __restrict__ Bias, char* __restrict__ Out,
    int rowsX, int rowsO, int Yt, int mode)
{
    __shared__ char AB[2][33024];   // 258 rows x 128 B, double-buffered

    const int tid = threadIdx.x;
    const int l   = tid & 63;
    const int wid = tid >> 6;
    const int tl0 = l & 31;
    const int lh  = l >> 5;

    int p = blockIdx.x;
    int chunk = p >> 5, slot = p & 31;
    int gl = slot & 15, c = slot >> 4;
    int g = chunk * 16 + gl;
    int zb = g / Yt, y = g - zb * Yt;

    const int bt0 = y * 128;
    const int r0  = 2 * bt0;
    const char* Xb = Xp + (size_t)zb * (size_t)rowsX * 2048;

    f32x16 acc[4][2];
#pragma unroll
    for (int tp = 0; tp < 4; ++tp)
#pragma unroll
        for (int cp = 0; cp < 2; ++cp) acc[tp][cp] = (f32x16)(0.0f);

    const int cbase = c * 8 + wid * 2;

    auto stage = [&](char* buf, int cb) {
#pragma unroll
        for (int i = 0; i < 9; ++i) {
            int u = i * 256 + tid;
            if (u < CONV_UNITS2) {
                int r = u >> 3, ul = u & 7;
                int us = ul ^ ((r >> 1) & 7);
                const char* gp = Xb + (size_t)(r0 + r) * 2048
                               + (us >> 2) * 1024 + cb * 64 + (us & 3) * 16;
                gload_lds16(gp, buf + ((size_t)(i * 256 + wid * 64)) * 16);
            }
        }
    };

    stage(AB[0], 0);
    __syncthreads();

    for (int cb = 0; cb < 16; ++cb) {
        if (cb < 15) stage(AB[(cb + 1) & 1], cb + 1);
        const char* Ab = AB[cb & 1];
#pragma unroll
        for (int ph = 0; ph < 6; ++ph) {
            const int tap = ph >> 1, ks = ph & 1;
            bf16x8 a0[4], a1[4], bb[2][2];
#pragma unroll
            for (int tp = 0; tp < 4; ++tp) {
                int rl = 2 * (tp * 32 + tl0) + tap;
                int sw = (rl >> 1) & 7;
                int qb = ks * 2 + lh;
                a0[tp] = *(const bf16x8*)(Ab + rl * 128 + ((qb ^ sw) << 4));
                a1[tp] = *(const bf16x8*)(Ab + rl * 128 + (((qb + 4) ^ sw) << 4));
            }
#pragma unroll
            for (int cp = 0; cp < 2; ++cp) {
                size_t f0 = ((((size_t)(cb * 16 + cbase + cp) * 3 + tap) * 2 + 0) * 2 + ks);
                const char* wp = (const char*)Wf + f0 * 1024 + l * 16;
                bb[0][cp] = *(const bf16x8*)(wp);
                bb[1][cp] = *(const bf16x8*)(wp + 2048);
            }
#pragma unroll
            for (int tp = 0; tp < 4; ++tp)
#pragma unroll
                for (int cp = 0; cp < 2; ++cp) {
                    acc[tp][cp] = __builtin_amdgcn_mfma_f32_32x32x16_bf16(
                        a0[tp], bb[0][cp], acc[tp][cp], 0, 0, 0);
                    acc[tp][cp] = __builtin_amdgcn_mfma_f32_32x32x16_bf16(
                        a0[tp], bb[1][cp], acc[tp][cp], 0, 0, 0);
                    acc[tp][cp] = __builtin_amdgcn_mfma_f32_32x32x16_bf16(
                        a1[tp], bb[0][cp], acc[tp][cp], 0, 0, 0);
                }
        }
        __syncthreads();
    }

    const size_t outB = (size_t)zb * (size_t)rowsO * 2048;
    const int colb = c * 256 + wid * 64 + tl0;
#pragma unroll
    for (int cp = 0; cp < 2; ++cp) {
        int co = colb + cp * 32;
        float bv = Bias[co];
#pragma unroll
        for (int tp = 0; tp < 4; ++tp) {
            int trow = bt0 + tp * 32 + 4 * lh;
#pragma unroll
            for (int r = 0; r < 16; ++r) {
                int row = trow + (r & 3) + 8 * (r >> 2);
                float v = acc[tp][cp][r] + bv;
                v = v < 0.f ? 0.2f * v : v;
                char* po = Out + outB + (size_t)row * 2048;
                if (mode == 0) {
                    unsigned short hi = f2bf_rne(v);
                    unsigned short lo = f2bf_rne(v - bf2f(hi));
                    *(unsigned short*)(po + co * 2) = hi;
                    *(unsigned short*)(po + 1024 + co * 2) = lo;
                } else {
                    *(float*)(po + (size_t)co * 4) = v;
                }
            }
        }
    }
}

// ---------------------------------------------------------------------------
// conv3 + mod_sigmoid + IR synth + causal FIR + transpose. Input t-major fp32.
// ---------------------------------------------------------------------------
__global__ __launch_bounds__(256) void conv3_tmaj(
    const float* __restrict__ H2, const float* __restrict__ W3,
    const float* __restrict__ B3, const float* __restrict__ Noise,
    float* __restrict__ Out)
{
    __shared__ float W3s[1536][10];
    __shared__ float Xe[32][40];
    __shared__ float Xo[32][40];
    __shared__ float hs[32][12];

    const int b   = blockIdx.y;
    const int t0  = blockIdx.x * 32;
    const int tid = threadIdx.x;
    const int t   = tid & 31;
    const int gch = tid >> 5;

    for (int idx = tid; idx < 15360; idx += 256) {
        int co = idx / 1536;
        int r  = idx - co * 1536;
        W3s[r][co] = W3[idx];
    }

    float acc3[2] = {0.f, 0.f};
    const float* Hb = H2 + (size_t)b * 1026 * 512;

    for (int c0 = 0; c0 < 512; c0 += 32) {
        __syncthreads();
        for (int idx = tid; idx < 33 * 32; idx += 256) {
            int pp = idx >> 5, ci = idx & 31;
            Xe[ci][pp] = Hb[(size_t)(2 * t0 + 2 * pp) * 512 + c0 + ci];
            Xo[ci][pp] = Hb[(size_t)(2 * t0 + 2 * pp + 1) * 512 + c0 + ci];
        }
        __syncthreads();

        for (int ci = 0; ci < 32; ++ci) {
            float xe0 = Xe[ci][t];
            float xo0 = Xo[ci][t];
            float xe1 = Xe[ci][t + 1];
            int r = (c0 + ci) * 3;
#pragma unroll
            for (int m = 0; m < 2; ++m) {
                int cc = gch + m * 8;
                if (cc < 10) {
                    acc3[m] = fmaf(W3s[r][cc], xe0,
                              fmaf(W3s[r + 1][cc], xo0,
                              fmaf(W3s[r + 2][cc], xe1, acc3[m])));
                }
            }
        }
    }

#pragma unroll
    for (int m = 0; m < 2; ++m) {
        int cc = gch + m * 8;
        if (cc < 10) hs[t][cc] = acc3[m] + B3[cc];
    }
    __syncthreads();

    if (tid < 64) {
        const int tt = tid & 31;
        const int d  = tid >> 5;

        float A[5];
#pragma unroll
        for (int j = 0; j < 5; ++j) {
            float h = hs[tt][d * 5 + j] - 5.f;
            float s = 1.f / (1.f + expf(-h));
            A[j] = 2.f * powf(s, 2.3f) + 1e-7f;
        }

        const float SQ = 0.70710678118654752f;
        const float c1[8] = {1.f, SQ, 0.f, -SQ, -1.f, -SQ, 0.f, SQ};
        const float c2[8] = {1.f, 0.f, -1.f, 0.f, 1.f, 0.f, -1.f, 0.f};
        const float c3[8] = {1.f, -SQ, 0.f, SQ, -1.f, SQ, 0.f, -SQ};
        const float c4[8] = {1.f, -1.f, 1.f, -1.f, 1.f, -1.f, 1.f, -1.f};
        const float wsh[8] = {1.f, 0.85355339059327376f, 0.5f, 0.14644660940672624f,
                              0.f, 0.14644660940672624f, 0.5f, 0.85355339059327376f};

        float ir[8];
#pragma unroll
        for (int n = 0; n < 8; ++n) {
            float v = A[0] + 2.f * (A[1] * c1[n] + A[2] * c2[n] + A[3] * c3[n])
                    + A[4] * c4[n];
            ir[n] = 0.125f * v * wsh[n];
        }

        const float* npi = Noise + (size_t)b * 8192 + (size_t)(t0 + tt) * 16 + d * 8;
        float nz[8];
#pragma unroll
        for (int j = 0; j < 8; ++j) nz[j] = 2.f * npi[j] - 1.f;

        float* op = Out + (size_t)b * 8192 + (size_t)d * 4096 + (size_t)(t0 + tt) * 8;
#pragma unroll
        for (int o = 0; o < 8; ++o) {
            float s = 0.f;
#pragma unroll
            for (int j = 0; j <= o; ++j) s += nz[j] * ir[o - j];
            op[o] = s;
        }
    }
}

// ===========================================================================
// Fallback path: round-1 fp32 kernels (verified correct).
// ===========================================================================
#define BCO 64
#define BT  128
#define KC  16

__global__ __launch_bounds__(256, 2) void conv_s2_kernel(
    const float* __restrict__ X, const float* __restrict__ W,
    const float* __restrict__ Bias, float* __restrict__ Y,
    int Cin, int Tin, int Cout, int Tout, int leaky)
{
    __shared__ float Xe[KC][132];
    __shared__ float Xo[KC][132];
    __shared__ float Wk[KC * 3][68];

    const int b   = blockIdx.z;
    const int co0 = blockIdx.y * BCO;
    const int t0  = blockIdx.x * BT;
    const int tid = threadIdx.x;
    const int ty  = tid & 15;
    const int tx  = tid >> 4;

    const float* Xb = X + (size_t)b * Cin * Tin;

    float acc[4][8];
#pragma unroll
    for (int i = 0; i < 4; ++i)
#pragma unroll
        for (int j = 0; j < 8; ++j) acc[i][j] = 0.f;

    for (int c0 = 0; c0 < Cin; c0 += KC) {
        __syncthreads();
        for (int idx = tid; idx < KC * 130; idx += 256) {
            int ci = idx / 130;
            int pp = idx - ci * 130;
            int gt = 2 * t0 + 2 * pp;
            const float* src = Xb + (size_t)(c0 + ci) * Tin;
            float e, o;
            if (gt + 1 < Tin) {
                float2 v = *(const float2*)(src + gt);
                e = v.x; o = v.y;
            } else {
                e = (gt < Tin) ? src[gt] : 0.f;
                o = 0.f;
            }
            Xe[ci][pp] = e;
            Xo[ci][pp] = o;
        }
        {
            const float* Wc = W + (size_t)co0 * Cin * 3 + (size_t)c0 * 3;
            for (int idx = tid; idx < BCO * (KC * 3); idx += 256) {
                int co = idx / 48;
                int r  = idx - co * 48;
                Wk[r][co] = Wc[(size_t)co * Cin * 3 + r];
            }
        }
        __syncthreads();

#pragma unroll
        for (int ci = 0; ci < KC; ++ci) {
            float4 xe0 = *(const float4*)&Xe[ci][tx * 8];
            float4 xe1 = *(const float4*)&Xe[ci][tx * 8 + 4];
            float  xe8 = Xe[ci][tx * 8 + 8];
            float4 xo0 = *(const float4*)&Xo[ci][tx * 8];
            float4 xo1 = *(const float4*)&Xo[ci][tx * 8 + 4];
            float4 w0  = *(const float4*)&Wk[ci * 3 + 0][ty * 4];
            float4 w1  = *(const float4*)&Wk[ci * 3 + 1][ty * 4];
            float4 w2  = *(const float4*)&Wk[ci * 3 + 2][ty * 4];
            float xe[9] = {xe0.x, xe0.y, xe0.z, xe0.w, xe1.x, xe1.y, xe1.z, xe1.w, xe8};
            float xo[8] = {xo0.x, xo0.y, xo0.z, xo0.w, xo1.x, xo1.y, xo1.z, xo1.w};
            float wa[3][4] = {{w0.x, w0.y, w0.z, w0.w},
                              {w1.x, w1.y, w1.z, w1.w},
                              {w2.x, w2.y, w2.z, w2.w}};
#pragma unroll
            for (int i = 0; i < 4; ++i)
#pragma unroll
                for (int j = 0; j < 8; ++j)
                    acc[i][j] = fmaf(wa[0][i], xe[j],
                                fmaf(wa[1][i], xo[j],
                                fmaf(wa[2][i], xe[j + 1], acc[i][j])));
        }
    }

    float* Yb = Y + (size_t)b * Cout * Tout;
#pragma unroll
    for (int i = 0; i < 4; ++i) {
        int   co = co0 + ty * 4 + i;
        float bv = Bias[co];
        float ov[8];
#pragma unroll
        for (int j = 0; j < 8; ++j) {
            float v = acc[i][j] + bv;
            ov[j] = (leaky && v < 0.f) ? 0.2f * v : v;
        }
        float* dst = Yb + (size_t)co * Tout + t0 + tx * 8;
        *(float4*)dst       = make_float4(ov[0], ov[1], ov[2], ov[3]);
        *(float4*)(dst + 4) = make_float4(ov[4], ov[5], ov[6], ov[7]);
    }
}

__global__ __launch_bounds__(256) void conv3_cmaj(
    const float* __restrict__ H2, const float* __restrict__ W3,
    const float* __restrict__ B3, const float* __restrict__ Noise,
    float* __restrict__ Out)
{
    __shared__ float W3s[1536][10];
    __shared__ float Xe[32][40];
    __shared__ float Xo[32][40];
    __shared__ float hs[32][12];

    const int b   = blockIdx.y;
    const int t0  = blockIdx.x * 32;
    const int tid = threadIdx.x;
    const int t   = tid & 31;
    const int gch = tid >> 5;

    for (int idx = tid; idx < 15360; idx += 256) {
        int co = idx / 1536;
        int r  = idx - co * 1536;
        W3s[r][co] = W3[idx];
    }

    float acc3[2] = {0.f, 0.f};
    const float* Hb = H2 + (size_t)b * 512 * 1024;

    for (int c0 = 0; c0 < 512; c0 += 32) {
        __syncthreads();
        for (int idx = tid; idx < 32 * 33; idx += 256) {
            int ci = idx / 33;
            int pp = idx - ci * 33;
            int gt = 2 * t0 + 2 * pp;
            const float* src = Hb + (size_t)(c0 + ci) * 1024;
            float e, o;
            if (gt + 1 < 1024) {
                float2 v = *(const float2*)(src + gt);
                e = v.x; o = v.y;
            } else {
                e = (gt < 1024) ? src[gt] : 0.f;
                o = 0.f;
            }
            Xe[ci][pp] = e;
            Xo[ci][pp] = o;
        }
        __syncthreads();

        for (int ci = 0; ci < 32; ++ci) {
            float xe0 = Xe[ci][t];
            float xo0 = Xo[ci][t];
            float xe1 = Xe[ci][t + 1];
            int r = (c0 + ci) * 3;
#pragma unroll
            for (int m = 0; m < 2; ++m) {
                int cc = gch + m * 8;
                if (cc < 10)
                    acc3[m] = fmaf(W3s[r][cc], xe0,
                              fmaf(W3s[r + 1][cc], xo0,
                              fmaf(W3s[r + 2][cc], xe1, acc3[m])));
            }
        }
    }

#pragma unroll
    for (int m = 0; m < 2; ++m) {
        int cc = gch + m * 8;
        if (cc < 10) hs[t][cc] = acc3[m] + B3[cc];
    }
    __syncthreads();

    if (tid < 64) {
        const int tt = tid & 31;
        const int d  = tid >> 5;
        float A[5];
#pragma unroll
        for (int j = 0; j < 5; ++j) {
            float h = hs[tt][d * 5 + j] - 5.f;
            float s = 1.f / (1.f + expf(-h));
            A[j] = 2.f * powf(s, 2.3f) + 1e-7f;
        }
        const float SQ = 0.70710678118654752f;
        const float c1[8] = {1.f, SQ, 0.f, -SQ, -1.f, -SQ, 0.f, SQ};
        const float c2[8] = {1.f, 0.f, -1.f, 0.f, 1.f, 0.f, -1.f, 0.f};
        const float c3[8] = {1.f, -SQ, 0.f, SQ, -1.f, SQ, 0.f, -SQ};
        const float c4[8] = {1.f, -1.f, 1.f, -1.f, 1.f, -1.f, 1.f, -1.f};
        const float wsh[8] = {1.f, 0.85355339059327376f, 0.5f, 0.14644660940672624f,
                              0.f, 0.14644660940672624f, 0.5f, 0.85355339059327376f};
        float ir[8];
#pragma unroll
        for (int n = 0; n < 8; ++n) {
            float v = A[0] + 2.f * (A[1] * c1[n] + A[2] * c2[n] + A[3] * c3[n])
                    + A[4] * c4[n];
            ir[n] = 0.125f * v * wsh[n];
        }
        const float* npi = Noise + (size_t)b * 8192 + (size_t)(t0 + tt) * 16 + d * 8;
        float nz[8];
#pragma unroll
        for (int j = 0; j < 8; ++j) nz[j] = 2.f * npi[j] - 1.f;
        float* op = Out + (size_t)b * 8192 + (size_t)d * 4096 + (size_t)(t0 + tt) * 8;
#pragma unroll
        for (int o = 0; o < 8; ++o) {
            float s = 0.f;
#pragma unroll
            for (int j = 0; j <= o; ++j) s += nz[j] * ir[o - j];
            op[o] = s;
        }
    }
}

// ===========================================================================
extern "C" void kernel_launch(void* const* d_in, const int* in_sizes, int n_in,
                              void* d_out, int out_size, void* d_ws, size_t ws_size,
                              hipStream_t stream) {
    const float* x     = (const float*)d_in[0];
    const float* noise = (const float*)d_in[1];
    const float* w1    = (const float*)d_in[2];
    const float* b1    = (const float*)d_in[3];
    const float* w2    = (const float*)d_in[4];
    const float* b2    = (const float*)d_in[5];
    const float* w3    = (const float*)d_in[6];
    const float* b3    = (const float*)d_in[7];
    float* out = (float*)d_out;

    const size_t H1P_BYTES = (size_t)16 * 2080 * 2048;      //  68,157,440
    const size_t H2T_BYTES = (size_t)16 * 1026 * 512 * 4;   //  33,619,968
    const size_t WF_BYTES  = (size_t)512 * 512 * 3 * 2 * 2; //   3,145,728
    const size_t NEED = H1P_BYTES + H2T_BYTES + 2 * WF_BYTES; // ~108 MB

    if (ws_size >= NEED) {
        char*  h1p = (char*)d_ws;
        char*  h2t = h1p + H1P_BYTES;
        short* Wf1 = (short*)(h2t + H2T_BYTES);
        short* Wf2 = (short*)((char*)Wf1 + WF_BYTES);

        prep_w_kernel<<<768, 256, 0, stream>>>(w1, Wf1);
        prep_w_kernel<<<768, 256, 0, stream>>>(w2, Wf2);
        zero_pads<<<128, 256, 0, stream>>>(h1p, h2t);
        // conv1 (fused transpose/split): grid 512 = 2 co-halves x 16 x 16
        conv1_fused<<<512, 256, 0, stream>>>(x, Wf1, b1, h1p);
        // conv2: Yt = 1024/128 = 8, grid = 2*8*16 = 256
        conv_mfma<<<256, 256, 0, stream>>>(h1p, Wf2, b2, h2t, 2080, 1026, 8, 1);
        conv3_tmaj<<<dim3(16, 16), 256, 0, stream>>>((const float*)h2t, w3, b3, noise, out);
    } else {
        float* h1 = (float*)d_ws;
        float* h2 = h1 + (size_t)16 * 512 * 2048;
        dim3 blk(256);
        conv_s2_kernel<<<dim3(2048 / BT, 512 / BCO, 16), blk, 0, stream>>>(
            x, w1, b1, h1, 512, 4096, 512, 2048, 1);
        conv_s2_kernel<<<dim3(1024 / BT, 512 / BCO, 16), blk, 0, stream>>>(
            h1, w2, b2, h2, 512, 2048, 512, 1024, 1);
        conv3_cmaj<<<dim3(16, 16), blk, 0, stream>>>(h2, w3, b3, noise, out);
    }
}

// Round 13
// 313.153 us; speedup vs baseline: 1.1332x; 1.1332x over previous
//
#include <hip/hip_runtime.h>
#include <math.h>

// ===========================================================================
// RAVE noise generator.
//  x:[16][512][4096] w1,w2:[512][512][3] w3:[10][512][3] noise:[16][512][2][8]
//  out:[16][2][4096]
//
// Fast path (split-bf16 MFMA):
//   prep_w:  w -> Wf frag-order split-bf16 (MFMA B-operand layout)
//   conv1_fused: x (fp32, reg-staged + in-kernel transpose/split) -> h1p
//   conv_mfma (conv2): h1p -> h2t fp32 t-major [b][1026][512], leaky (R2-exact)
//   conv3_tmaj: fused conv3 + mod_sigmoid + IR + causal FIR + transpose
// Round-13: FINAL revert to the verified optimum (R8/R11, 313.5-314.5 us,
// reproduced twice). Falsification ledger for the 2-barrier structure:
// R3 B-hoist, R5 dist-1, R6 wide-co, R9 interleave, R10 narrow-t/2xTLP,
// R12 wide-t — all null or negative. This config is the local optimum.
// ===========================================================================

typedef __attribute__((ext_vector_type(8)))  short bf16x8;
typedef __attribute__((ext_vector_type(16))) float f32x16;

__device__ __forceinline__ unsigned short f2bf_rne(float f) {
    unsigned int u = __float_as_uint(f);
    unsigned int r = u + 0x7fff + ((u >> 16) & 1);
    return (unsigned short)(r >> 16);
}
__device__ __forceinline__ float bf2f(unsigned short h) {
    return __uint_as_float(((unsigned int)h) << 16);
}
__device__ __forceinline__ void gload_lds16(const void* g, void* l) {
    __builtin_amdgcn_global_load_lds(
        (const __attribute__((address_space(1))) unsigned int*)g,
        (__attribute__((address_space(3))) unsigned int*)l, 16, 0, 0);
}
__device__ __forceinline__ int swz1(int r) {        // conv1_fused swizzle
    return ((r >> 1) ^ (r >> 4)) & 7;
}

// ---------------------------------------------------------------------------
// prep_w: w[co][ci][3] fp32 -> frag-order split-bf16.
// frag f = (((cb*16 + cob)*3 + tap)*2 + hl)*2 + ks ; 1 KB per frag;
// lane l holds B[ci = cb*32 + ks*16 + (l>>5)*8 + j][co = cob*32 + (l&31)].
// ---------------------------------------------------------------------------
__global__ void prep_w_kernel(const float* __restrict__ W, short* __restrict__ Wf)
{
    int gid = blockIdx.x * 256 + threadIdx.x;   // 0..196607
    int f = gid >> 6, l = gid & 63;
    int ks = f & 1, hl = (f >> 1) & 1;
    int k  = (f >> 2) % 3;
    int rem = (f >> 2) / 3;
    int cob = rem & 15, cb = rem >> 4;
    int co  = cob * 32 + (l & 31);
    int ci0 = cb * 32 + ks * 16 + (l >> 5) * 8;
    bf16x8 o;
#pragma unroll
    for (int j = 0; j < 8; ++j) {
        float v = W[((size_t)co * 512 + ci0 + j) * 3 + k];
        unsigned short hi = f2bf_rne(v);
        o[j] = hl ? (short)f2bf_rne(v - bf2f(hi)) : (short)hi;
    }
    *(bf16x8*)((char*)Wf + (size_t)f * 1024 + l * 16) = o;
}

// zero pad rows: h1p row 2048 region (4KB/b) + h2t rows 1024-1025 (4KB/b)
__global__ void zero_pads(char* __restrict__ h1p, char* __restrict__ h2t) {
    int id = blockIdx.x * 256 + threadIdx.x;    // 32768 threads
    if (id < 16384) {
        int b = id >> 10, w = id & 1023;
        *(float*)(h1p + ((size_t)b * 2080 + 2048) * 2048 + (size_t)w * 4) = 0.f;
    } else {
        int id2 = id - 16384;
        int b = id2 >> 10, w = id2 & 1023;
        *(float*)(h2t + ((size_t)b * 1026 + 1024) * 2048 + (size_t)w * 4) = 0.f;
    }
}

// ---------------------------------------------------------------------------
// conv1_fused: stride-2 k=3 conv as implicit GEMM, split-bf16, 32x32x16 MFMA,
// reading x (fp32 [b][ci][t]) DIRECTLY. Per K-step (32 ci):
//   1. load 12 B frags (phases 0-2); issue 4-5 float4 x loads for tile cb+1
//   2. phases 0-2 MFMA; load 12 B frags (phases 3-5); phases 3-5 MFMA
//   3. convert fp32->split-bf16 (trunc hi) and ds_write into AB[(cb+1)&1]
//   4. __syncthreads
// Block: 64 t x 256 co, 4 waves (wave = 64t x 64co = 2x2 frags).
// ---------------------------------------------------------------------------
__global__ __launch_bounds__(256, 2) void conv1_fused(
    const float* __restrict__ X, const short* __restrict__ Wf,
    const float* __restrict__ Bias, char* __restrict__ Out)
{
    __shared__ char AB[2][16512];   // 129 rows x 128 B, double-buffered

    const int tid = threadIdx.x;
    const int l   = tid & 63;
    const int wid = tid >> 6;
    const int tl0 = l & 31;
    const int lh  = l >> 5;

    // block swizzle: pair the 2 co-tiles of a (b, t-tile) on the same XCD
    int p = blockIdx.x;
    int chunk = p >> 5, slot = p & 31;
    int gl = slot & 15, c = slot >> 4;
    int g = chunk * 16 + gl;
    int zb = g >> 5, y = g & 31;          // Yt = 32 for conv1

    const int bt0 = y * 64;
    const int r0  = 2 * bt0;
    const float* Xb = X + (size_t)zb * 512 * 4096;

    // staging thread mapping: 16 row-groups x 16 ci-pairs
    const int rg   = tid & 15;            // rows rg*8 .. rg*8+7
    const int cip  = tid >> 4;            // ci = 2*cip, 2*cip+1
    const int ci   = 2 * cip;
    const int u_hi = ci >> 3;             // 0..3
    const int u_lo = 4 + u_hi;
    const int coff = (ci & 7) * 2;        // 0,4,8,12 (4B aligned)

    f32x16 acc[2][2];
#pragma unroll
    for (int tp = 0; tp < 2; ++tp)
#pragma unroll
        for (int cp = 0; cp < 2; ++cp) acc[tp][cp] = (f32x16)(0.0f);

    const int cbase = c * 8 + wid * 2;    // co-unit base (32co units)

    float4 fx0, fx1, fx2, fx3;            // staged rows (2 ci x 8 rows)
    float  fextra = 0.f;                  // row 128 (tid<32 only)

    auto issue_loads = [&](int cb) {
        const float* s0 = Xb + (size_t)(cb * 32 + 2 * cip) * 4096 + r0 + rg * 8;
        fx0 = *(const float4*)(s0);
        fx1 = *(const float4*)(s0 + 4);
        fx2 = *(const float4*)(s0 + 4096);
        fx3 = *(const float4*)(s0 + 4100);
        if (tid < 32) {
            int rr = r0 + 128;
            fextra = (rr < 4096) ? Xb[(size_t)(cb * 32 + tid) * 4096 + rr] : 0.f;
        }
    };

    auto write_tile = [&](char* buf) {
        float va[8] = {fx0.x, fx0.y, fx0.z, fx0.w, fx1.x, fx1.y, fx1.z, fx1.w};
        float vb[8] = {fx2.x, fx2.y, fx2.z, fx2.w, fx3.x, fx3.y, fx3.z, fx3.w};
#pragma unroll
        for (int k = 0; k < 8; ++k) {
            int r  = rg * 8 + k;
            int sw = swz1(r);
            unsigned int ua = __float_as_uint(va[k]);
            unsigned int ub = __float_as_uint(vb[k]);
            float ha = __uint_as_float(ua & 0xffff0000u);   // trunc hi
            float hb = __uint_as_float(ub & 0xffff0000u);
            unsigned short l0 = f2bf_rne(va[k] - ha);       // exact residual
            unsigned short l1 = f2bf_rne(vb[k] - hb);
            *(unsigned int*)(buf + r * 128 + (((u_hi ^ sw)) << 4) + coff) =
                (ua >> 16) | (ub & 0xffff0000u);
            *(unsigned int*)(buf + r * 128 + (((u_lo ^ sw)) << 4) + coff) =
                (unsigned int)l0 | ((unsigned int)l1 << 16);
        }
        if (tid < 32) {
            int sw = swz1(128);
            unsigned int ue = __float_as_uint(fextra);
            float he = __uint_as_float(ue & 0xffff0000u);
            unsigned short lo = f2bf_rne(fextra - he);
            int uh = (tid >> 3) ^ sw;
            int ul = (4 + (tid >> 3)) ^ sw;
            *(unsigned short*)(buf + 128 * 128 + (uh << 4) + (tid & 7) * 2) =
                (unsigned short)(ue >> 16);
            *(unsigned short*)(buf + 128 * 128 + (ul << 4) + (tid & 7) * 2) = lo;
        }
    };

    // B-frag pointer: f = ((co_unit*3 + tap)*2 + hl)*2 + ks, 1 KB per frag
    auto wptr = [&](int cb_, int cp, int tap, int ks, int hl) -> const char* {
        size_t f0 = ((((size_t)(cb_ * 16 + cbase + cp) * 3 + tap) * 2 + hl) * 2 + ks);
        return (const char*)Wf + f0 * 1024 + (size_t)l * 16;
    };

    // prologue: tile 0 into AB[0]
    issue_loads(0);
    write_tile(AB[0]);
    __syncthreads();

    for (int cb = 0; cb < 16; ++cb) {
        const char* Ab = AB[cb & 1];

        // ---- group A: B frags for phases 0..2 (tap,ks = 00,01,10)
        bf16x8 bbA[12];                    // [ph*4 + cp*2 + hl], static idx
#pragma unroll
        for (int ph = 0; ph < 3; ++ph)
#pragma unroll
            for (int cp = 0; cp < 2; ++cp)
#pragma unroll
                for (int hl = 0; hl < 2; ++hl)
                    bbA[ph * 4 + cp * 2 + hl] =
                        *(const bf16x8*)wptr(cb, cp, ph >> 1, ph & 1, hl);
        // ---- x loads for next tile (behind B in the vmcnt FIFO)
        if (cb < 15) issue_loads(cb + 1);

#pragma unroll
        for (int ph = 0; ph < 3; ++ph) {
            const int tap = ph >> 1, ks = ph & 1;
            bf16x8 a0[2], a1[2];
#pragma unroll
            for (int tp = 0; tp < 2; ++tp) {
                int rl = 2 * (tp * 32 + tl0) + tap;
                int sw = swz1(rl);
                int qb = ks * 2 + lh;
                a0[tp] = *(const bf16x8*)(Ab + rl * 128 + ((qb ^ sw) << 4));
                a1[tp] = *(const bf16x8*)(Ab + rl * 128 + (((qb + 4) ^ sw) << 4));
            }
#pragma unroll
            for (int tp = 0; tp < 2; ++tp)
#pragma unroll
                for (int cp = 0; cp < 2; ++cp) {
                    acc[tp][cp] = __builtin_amdgcn_mfma_f32_32x32x16_bf16(
                        a0[tp], bbA[ph * 4 + cp * 2 + 0], acc[tp][cp], 0, 0, 0);
                    acc[tp][cp] = __builtin_amdgcn_mfma_f32_32x32x16_bf16(
                        a0[tp], bbA[ph * 4 + cp * 2 + 1], acc[tp][cp], 0, 0, 0);
                    acc[tp][cp] = __builtin_amdgcn_mfma_f32_32x32x16_bf16(
                        a1[tp], bbA[ph * 4 + cp * 2 + 0], acc[tp][cp], 0, 0, 0);
                }
        }

        // ---- group B: B frags for phases 3..5 (tap,ks = 11,20,21)
        bf16x8 bbB[12];
#pragma unroll
        for (int ph = 3; ph < 6; ++ph)
#pragma unroll
            for (int cp = 0; cp < 2; ++cp)
#pragma unroll
                for (int hl = 0; hl < 2; ++hl)
                    bbB[(ph - 3) * 4 + cp * 2 + hl] =
                        *(const bf16x8*)wptr(cb, cp, ph >> 1, ph & 1, hl);

#pragma unroll
        for (int ph = 3; ph < 6; ++ph) {
            const int tap = ph >> 1, ks = ph & 1;
            bf16x8 a0[2], a1[2];
#pragma unroll
            for (int tp = 0; tp < 2; ++tp) {
                int rl = 2 * (tp * 32 + tl0) + tap;
                int sw = swz1(rl);
                int qb = ks * 2 + lh;
                a0[tp] = *(const bf16x8*)(Ab + rl * 128 + ((qb ^ sw) << 4));
                a1[tp] = *(const bf16x8*)(Ab + rl * 128 + (((qb + 4) ^ sw) << 4));
            }
#pragma unroll
            for (int tp = 0; tp < 2; ++tp)
#pragma unroll
                for (int cp = 0; cp < 2; ++cp) {
                    acc[tp][cp] = __builtin_amdgcn_mfma_f32_32x32x16_bf16(
                        a0[tp], bbB[(ph - 3) * 4 + cp * 2 + 0], acc[tp][cp], 0, 0, 0);
                    acc[tp][cp] = __builtin_amdgcn_mfma_f32_32x32x16_bf16(
                        a0[tp], bbB[(ph - 3) * 4 + cp * 2 + 1], acc[tp][cp], 0, 0, 0);
                    acc[tp][cp] = __builtin_amdgcn_mfma_f32_32x32x16_bf16(
                        a1[tp], bbB[(ph - 3) * 4 + cp * 2 + 0], acc[tp][cp], 0, 0, 0);
                }
        }

        if (cb < 15) write_tile((char*)AB[(cb + 1) & 1]);
        __syncthreads();
    }

    // ---- epilogue: bias + leaky, split-bf16 packed store to h1p (trunc hi)
    const size_t outB = (size_t)zb * 2080 * 2048;
    const int colb = c * 256 + wid * 64 + tl0;
#pragma unroll
    for (int cp = 0; cp < 2; ++cp) {
        int co = colb + cp * 32;
        float bv = Bias[co];
#pragma unroll
        for (int tp = 0; tp < 2; ++tp) {
            int trow = bt0 + tp * 32 + 4 * lh;
#pragma unroll
            for (int r = 0; r < 16; ++r) {
                int row = trow + (r & 3) + 8 * (r >> 2);
                float v = acc[tp][cp][r] + bv;
                v = v < 0.f ? 0.2f * v : v;
                char* po = Out + outB + (size_t)row * 2048;
                unsigned int uv = __float_as_uint(v);
                float hf = __uint_as_float(uv & 0xffff0000u);
                *(unsigned short*)(po + co * 2) = (unsigned short)(uv >> 16);
                *(unsigned short*)(po + 1024 + co * 2) = f2bf_rne(v - hf);
            }
        }
    }
}

// ---------------------------------------------------------------------------
// conv_mfma (R2-exact): used for conv2. gload_lds A staging from packed h1p.
// Block: 64 t x 256 co, 4 waves (wave = 64t x 64co = 2x2 frags).
// mode 1: fp32 t-major output (h2t).
// ---------------------------------------------------------------------------
#define CONV_UNITS 1032   // 129 rows * 8 x 16B units

__global__ __launch_bounds__(256, 2) void conv_mfma(
    const char* __restrict__ Xp, const short* __restrict__ Wf,
    const float* __restrict__ Bias, char* __restrict__ Out,
    int rowsX, int rowsO, int Yt, int mode)
{
    __shared__ char AB[2][16512];   // 129 rows x 128 B, double-buffered

    const int tid = threadIdx.x;
    const int l   = tid & 63;
    const int wid = tid >> 6;
    const int tl0 = l & 31;
    const int lh  = l >> 5;

    int p = blockIdx.x;
    int chunk = p >> 5, slot = p & 31;
    int gl = slot & 15, c = slot >> 4;
    int g = chunk * 16 + gl;
    int zb = g / Yt, y = g - zb * Yt;

    const int bt0 = y * 64;
    const int r0  = 2 * bt0;
    const char* Xb = Xp + (size_t)zb * (size_t)rowsX * 2048;

    f32x16 acc[2][2];
#pragma unroll
    for (int tp = 0; tp < 2; ++tp)
#pragma unroll
        for (int cp = 0; cp < 2; ++cp) acc[tp][cp] = (f32x16)(0.0f);

    const int cbase = c * 8 + wid * 2;

    auto stage = [&](char* buf, int cb) {
#pragma unroll
        for (int i = 0; i < 5; ++i) {
            int u = i * 256 + tid;
            if (u < CONV_UNITS) {
                int r = u >> 3, ul = u & 7;
                int us = ul ^ ((r >> 1) & 7);
                const char* gp = Xb + (size_t)(r0 + r) * 2048
                               + (us >> 2) * 1024 + cb * 64 + (us & 3) * 16;
                gload_lds16(gp, buf + ((size_t)(i * 256 + wid * 64)) * 16);
            }
        }
    };

    stage(AB[0], 0);
    __syncthreads();

    for (int cb = 0; cb < 16; ++cb) {
        if (cb < 15) stage(AB[(cb + 1) & 1], cb + 1);
        const char* Ab = AB[cb & 1];
#pragma unroll
        for (int ph = 0; ph < 6; ++ph) {
            const int tap = ph >> 1, ks = ph & 1;
            bf16x8 a[2][2], bb[2][2];
#pragma unroll
            for (int tp = 0; tp < 2; ++tp) {
                int rl = 2 * (tp * 32 + tl0) + tap;
                int sw = (rl >> 1) & 7;
                int qb = ks * 2 + lh;
                a[0][tp] = *(const bf16x8*)(Ab + rl * 128 + ((qb ^ sw) << 4));
                a[1][tp] = *(const bf16x8*)(Ab + rl * 128 + (((qb + 4) ^ sw) << 4));
            }
#pragma unroll
            for (int cp = 0; cp < 2; ++cp) {
                size_t f0 = ((((size_t)(cb * 16 + cbase + cp) * 3 + tap) * 2 + 0) * 2 + ks);
                const char* wp = (const char*)Wf + f0 * 1024 + l * 16;
                bb[0][cp] = *(const bf16x8*)(wp);
                bb[1][cp] = *(const bf16x8*)(wp + 2048);
            }
#pragma unroll
            for (int tp = 0; tp < 2; ++tp)
#pragma unroll
                for (int cp = 0; cp < 2; ++cp) {
                    acc[tp][cp] = __builtin_amdgcn_mfma_f32_32x32x16_bf16(
                        a[0][tp], bb[0][cp], acc[tp][cp], 0, 0, 0);
                    acc[tp][cp] = __builtin_amdgcn_mfma_f32_32x32x16_bf16(
                        a[0][tp], bb[1][cp], acc[tp][cp], 0, 0, 0);
                    acc[tp][cp] = __builtin_amdgcn_mfma_f32_32x32x16_bf16(
                        a[1][tp], bb[0][cp], acc[tp][cp], 0, 0, 0);
                }
        }
        __syncthreads();
    }

    const size_t outB = (size_t)zb * (size_t)rowsO * 2048;
    const int colb = c * 256 + wid * 64 + tl0;
#pragma unroll
    for (int cp = 0; cp < 2; ++cp) {
        int co = colb + cp * 32;
        float bv = Bias[co];
#pragma unroll
        for (int tp = 0; tp < 2; ++tp) {
            int trow = bt0 + tp * 32 + 4 * lh;
#pragma unroll
            for (int r = 0; r < 16; ++r) {
                int row = trow + (r & 3) + 8 * (r >> 2);
                float v = acc[tp][cp][r] + bv;
                v = v < 0.f ? 0.2f * v : v;
                char* po = Out + outB + (size_t)row * 2048;
                if (mode == 0) {
                    unsigned short hi = f2bf_rne(v);
                    unsigned short lo = f2bf_rne(v - bf2f(hi));
                    *(unsigned short*)(po + co * 2) = hi;
                    *(unsigned short*)(po + 1024 + co * 2) = lo;
                } else {
                    *(float*)(po + (size_t)co * 4) = v;
                }
            }
        }
    }
}

// ---------------------------------------------------------------------------
// conv3 + mod_sigmoid + IR synth + causal FIR + transpose. Input t-major fp32.
// ---------------------------------------------------------------------------
__global__ __launch_bounds__(256) void conv3_tmaj(
    const float* __restrict__ H2, const float* __restrict__ W3,
    const float* __restrict__ B3, const float* __restrict__ Noise,
    float* __restrict__ Out)
{
    __shared__ float W3s[1536][10];
    __shared__ float Xe[32][40];
    __shared__ float Xo[32][40];
    __shared__ float hs[32][12];

    const int b   = blockIdx.y;
    const int t0  = blockIdx.x * 32;
    const int tid = threadIdx.x;
    const int t   = tid & 31;
    const int gch = tid >> 5;

    for (int idx = tid; idx < 15360; idx += 256) {
        int co = idx / 1536;
        int r  = idx - co * 1536;
        W3s[r][co] = W3[idx];
    }

    float acc3[2] = {0.f, 0.f};
    const float* Hb = H2 + (size_t)b * 1026 * 512;

    for (int c0 = 0; c0 < 512; c0 += 32) {
        __syncthreads();
        for (int idx = tid; idx < 33 * 32; idx += 256) {
            int pp = idx >> 5, ci = idx & 31;
            Xe[ci][pp] = Hb[(size_t)(2 * t0 + 2 * pp) * 512 + c0 + ci];
            Xo[ci][pp] = Hb[(size_t)(2 * t0 + 2 * pp + 1) * 512 + c0 + ci];
        }
        __syncthreads();

        for (int ci = 0; ci < 32; ++ci) {
            float xe0 = Xe[ci][t];
            float xo0 = Xo[ci][t];
            float xe1 = Xe[ci][t + 1];
            int r = (c0 + ci) * 3;
#pragma unroll
            for (int m = 0; m < 2; ++m) {
                int cc = gch + m * 8;
                if (cc < 10) {
                    acc3[m] = fmaf(W3s[r][cc], xe0,
                              fmaf(W3s[r + 1][cc], xo0,
                              fmaf(W3s[r + 2][cc], xe1, acc3[m])));
                }
            }
        }
    }

#pragma unroll
    for (int m = 0; m < 2; ++m) {
        int cc = gch + m * 8;
        if (cc < 10) hs[t][cc] = acc3[m] + B3[cc];
    }
    __syncthreads();

    if (tid < 64) {
        const int tt = tid & 31;
        const int d  = tid >> 5;

        float A[5];
#pragma unroll
        for (int j = 0; j < 5; ++j) {
            float h = hs[tt][d * 5 + j] - 5.f;
            float s = 1.f / (1.f + expf(-h));
            A[j] = 2.f * powf(s, 2.3f) + 1e-7f;
        }

        const float SQ = 0.70710678118654752f;
        const float c1[8] = {1.f, SQ, 0.f, -SQ, -1.f, -SQ, 0.f, SQ};
        const float c2[8] = {1.f, 0.f, -1.f, 0.f, 1.f, 0.f, -1.f, 0.f};
        const float c3[8] = {1.f, -SQ, 0.f, SQ, -1.f, SQ, 0.f, -SQ};
        const float c4[8] = {1.f, -1.f, 1.f, -1.f, 1.f, -1.f, 1.f, -1.f};
        const float wsh[8] = {1.f, 0.85355339059327376f, 0.5f, 0.14644660940672624f,
                              0.f, 0.14644660940672624f, 0.5f, 0.85355339059327376f};

        float ir[8];
#pragma unroll
        for (int n = 0; n < 8; ++n) {
            float v = A[0] + 2.f * (A[1] * c1[n] + A[2] * c2[n] + A[3] * c3[n])
                    + A[4] * c4[n];
            ir[n] = 0.125f * v * wsh[n];
        }

        const float* npi = Noise + (size_t)b * 8192 + (size_t)(t0 + tt) * 16 + d * 8;
        float nz[8];
#pragma unroll
        for (int j = 0; j < 8; ++j) nz[j] = 2.f * npi[j] - 1.f;

        float* op = Out + (size_t)b * 8192 + (size_t)d * 4096 + (size_t)(t0 + tt) * 8;
#pragma unroll
        for (int o = 0; o < 8; ++o) {
            float s = 0.f;
#pragma unroll
            for (int j = 0; j <= o; ++j) s += nz[j] * ir[o - j];
            op[o] = s;
        }
    }
}

// ===========================================================================
// Fallback path: round-1 fp32 kernels (verified correct).
// ===========================================================================
#define BCO 64
#define BT  128
#define KC  16

__global__ __launch_bounds__(256, 2) void conv_s2_kernel(
    const float* __restrict__ X, const float* __restrict__ W,
    const float* __restrict__ Bias, float* __restrict__ Y,
    int Cin, int Tin, int Cout, int Tout, int leaky)
{
    __shared__ float Xe[KC][132];
    __shared__ float Xo[KC][132];
    __shared__ float Wk[KC * 3][68];

    const int b   = blockIdx.z;
    const int co0 = blockIdx.y * BCO;
    const int t0  = blockIdx.x * BT;
    const int tid = threadIdx.x;
    const int ty  = tid & 15;
    const int tx  = tid >> 4;

    const float* Xb = X + (size_t)b * Cin * Tin;

    float acc[4][8];
#pragma unroll
    for (int i = 0; i < 4; ++i)
#pragma unroll
        for (int j = 0; j < 8; ++j) acc[i][j] = 0.f;

    for (int c0 = 0; c0 < Cin; c0 += KC) {
        __syncthreads();
        for (int idx = tid; idx < KC * 130; idx += 256) {
            int ci = idx / 130;
            int pp = idx - ci * 130;
            int gt = 2 * t0 + 2 * pp;
            const float* src = Xb + (size_t)(c0 + ci) * Tin;
            float e, o;
            if (gt + 1 < Tin) {
                float2 v = *(const float2*)(src + gt);
                e = v.x; o = v.y;
            } else {
                e = (gt < Tin) ? src[gt] : 0.f;
                o = 0.f;
            }
            Xe[ci][pp] = e;
            Xo[ci][pp] = o;
        }
        {
            const float* Wc = W + (size_t)co0 * Cin * 3 + (size_t)c0 * 3;
            for (int idx = tid; idx < BCO * (KC * 3); idx += 256) {
                int co = idx / 48;
                int r  = idx - co * 48;
                Wk[r][co] = Wc[(size_t)co * Cin * 3 + r];
            }
        }
        __syncthreads();

#pragma unroll
        for (int ci = 0; ci < KC; ++ci) {
            float4 xe0 = *(const float4*)&Xe[ci][tx * 8];
            float4 xe1 = *(const float4*)&Xe[ci][tx * 8 + 4];
            float  xe8 = Xe[ci][tx * 8 + 8];
            float4 xo0 = *(const float4*)&Xo[ci][tx * 8];
            float4 xo1 = *(const float4*)&Xo[ci][tx * 8 + 4];
            float4 w0  = *(const float4*)&Wk[ci * 3 + 0][ty * 4];
            float4 w1  = *(const float4*)&Wk[ci * 3 + 1][ty * 4];
            float4 w2  = *(const float4*)&Wk[ci * 3 + 2][ty * 4];
            float xe[9] = {xe0.x, xe0.y, xe0.z, xe0.w, xe1.x, xe1.y, xe1.z, xe1.w, xe8};
            float xo[8] = {xo0.x, xo0.y, xo0.z, xo0.w, xo1.x, xo1.y, xo1.z, xo1.w};
            float wa[3][4] = {{w0.x, w0.y, w0.z, w0.w},
                              {w1.x, w1.y, w1.z, w1.w},
                              {w2.x, w2.y, w2.z, w2.w}};
#pragma unroll
            for (int i = 0; i < 4; ++i)
#pragma unroll
                for (int j = 0; j < 8; ++j)
                    acc[i][j] = fmaf(wa[0][i], xe[j],
                                fmaf(wa[1][i], xo[j],
                                fmaf(wa[2][i], xe[j + 1], acc[i][j])));
        }
    }

    float* Yb = Y + (size_t)b * Cout * Tout;
#pragma unroll
    for (int i = 0; i < 4; ++i) {
        int   co = co0 + ty * 4 + i;
        float bv = Bias[co];
        float ov[8];
#pragma unroll
        for (int j = 0; j < 8; ++j) {
            float v = acc[i][j] + bv;
            ov[j] = (leaky && v < 0.f) ? 0.2f * v : v;
        }
        float* dst = Yb + (size_t)co * Tout + t0 + tx * 8;
        *(float4*)dst       = make_float4(ov[0], ov[1], ov[2], ov[3]);
        *(float4*)(dst + 4) = make_float4(ov[4], ov[5], ov[6], ov[7]);
    }
}

__global__ __launch_bounds__(256) void conv3_cmaj(
    const float* __restrict__ H2, const float* __restrict__ W3,
    const float* __restrict__ B3, const float* __restrict__ Noise,
    float* __restrict__ Out)
{
    __shared__ float W3s[1536][10];
    __shared__ float Xe[32][40];
    __shared__ float Xo[32][40];
    __shared__ float hs[32][12];

    const int b   = blockIdx.y;
    const int t0  = blockIdx.x * 32;
    const int tid = threadIdx.x;
    const int t   = tid & 31;
    const int gch = tid >> 5;

    for (int idx = tid; idx < 15360; idx += 256) {
        int co = idx / 1536;
        int r  = idx - co * 1536;
        W3s[r][co] = W3[idx];
    }

    float acc3[2] = {0.f, 0.f};
    const float* Hb = H2 + (size_t)b * 512 * 1024;

    for (int c0 = 0; c0 < 512; c0 += 32) {
        __syncthreads();
        for (int idx = tid; idx < 32 * 33; idx += 256) {
            int ci = idx / 33;
            int pp = idx - ci * 33;
            int gt = 2 * t0 + 2 * pp;
            const float* src = Hb + (size_t)(c0 + ci) * 1024;
            float e, o;
            if (gt + 1 < 1024) {
                float2 v = *(const float2*)(src + gt);
                e = v.x; o = v.y;
            } else {
                e = (gt < 1024) ? src[gt] : 0.f;
                o = 0.f;
            }
            Xe[ci][pp] = e;
            Xo[ci][pp] = o;
        }
        __syncthreads();

        for (int ci = 0; ci < 32; ++ci) {
            float xe0 = Xe[ci][t];
            float xo0 = Xo[ci][t];
            float xe1 = Xe[ci][t + 1];
            int r = (c0 + ci) * 3;
#pragma unroll
            for (int m = 0; m < 2; ++m) {
                int cc = gch + m * 8;
                if (cc < 10)
                    acc3[m] = fmaf(W3s[r][cc], xe0,
                              fmaf(W3s[r + 1][cc], xo0,
                              fmaf(W3s[r + 2][cc], xe1, acc3[m])));
            }
        }
    }

#pragma unroll
    for (int m = 0; m < 2; ++m) {
        int cc = gch + m * 8;
        if (cc < 10) hs[t][cc] = acc3[m] + B3[cc];
    }
    __syncthreads();

    if (tid < 64) {
        const int tt = tid & 31;
        const int d  = tid >> 5;
        float A[5];
#pragma unroll
        for (int j = 0; j < 5; ++j) {
            float h = hs[tt][d * 5 + j] - 5.f;
            float s = 1.f / (1.f + expf(-h));
            A[j] = 2.f * powf(s, 2.3f) + 1e-7f;
        }
        const float SQ = 0.70710678118654752f;
        const float c1[8] = {1.f, SQ, 0.f, -SQ, -1.f, -SQ, 0.f, SQ};
        const float c2[8] = {1.f, 0.f, -1.f, 0.f, 1.f, 0.f, -1.f, 0.f};
        const float c3[8] = {1.f, -SQ, 0.f, SQ, -1.f, SQ, 0.f, -SQ};
        const float c4[8] = {1.f, -1.f, 1.f, -1.f, 1.f, -1.f, 1.f, -1.f};
        const float wsh[8] = {1.f, 0.85355339059327376f, 0.5f, 0.14644660940672624f,
                              0.f, 0.14644660940672624f, 0.5f, 0.85355339059327376f};
        float ir[8];
#pragma unroll
        for (int n = 0; n < 8; ++n) {
            float v = A[0] + 2.f * (A[1] * c1[n] + A[2] * c2[n] + A[3] * c3[n])
                    + A[4] * c4[n];
            ir[n] = 0.125f * v * wsh[n];
        }
        const float* npi = Noise + (size_t)b * 8192 + (size_t)(t0 + tt) * 16 + d * 8;
        float nz[8];
#pragma unroll
        for (int j = 0; j < 8; ++j) nz[j] = 2.f * npi[j] - 1.f;
        float* op = Out + (size_t)b * 8192 + (size_t)d * 4096 + (size_t)(t0 + tt) * 8;
#pragma unroll
        for (int o = 0; o < 8; ++o) {
            float s = 0.f;
#pragma unroll
            for (int j = 0; j <= o; ++j) s += nz[j] * ir[o - j];
            op[o] = s;
        }
    }
}

// ===========================================================================
extern "C" void kernel_launch(void* const* d_in, const int* in_sizes, int n_in,
                              void* d_out, int out_size, void* d_ws, size_t ws_size,
                              hipStream_t stream) {
    const float* x     = (const float*)d_in[0];
    const float* noise = (const float*)d_in[1];
    const float* w1    = (const float*)d_in[2];
    const float* b1    = (const float*)d_in[3];
    const float* w2    = (const float*)d_in[4];
    const float* b2    = (const float*)d_in[5];
    const float* w3    = (const float*)d_in[6];
    const float* b3    = (const float*)d_in[7];
    float* out = (float*)d_out;

    const size_t H1P_BYTES = (size_t)16 * 2080 * 2048;      //  68,157,440
    const size_t H2T_BYTES = (size_t)16 * 1026 * 512 * 4;   //  33,619,968
    const size_t WF_BYTES  = (size_t)512 * 512 * 3 * 2 * 2; //   3,145,728
    const size_t NEED = H1P_BYTES + H2T_BYTES + 2 * WF_BYTES; // ~108 MB

    if (ws_size >= NEED) {
        char*  h1p = (char*)d_ws;
        char*  h2t = h1p + H1P_BYTES;
        short* Wf1 = (short*)(h2t + H2T_BYTES);
        short* Wf2 = (short*)((char*)Wf1 + WF_BYTES);

        prep_w_kernel<<<768, 256, 0, stream>>>(w1, Wf1);
        prep_w_kernel<<<768, 256, 0, stream>>>(w2, Wf2);
        zero_pads<<<128, 256, 0, stream>>>(h1p, h2t);
        // conv1 (fused transpose/split): grid 1024 = 2 co-halves x 32 x 16
        conv1_fused<<<1024, 256, 0, stream>>>(x, Wf1, b1, h1p);
        // conv2: Yt = 1024/64 = 16, grid = 2*16*16 = 512
        conv_mfma<<<512, 256, 0, stream>>>(h1p, Wf2, b2, h2t, 2080, 1026, 16, 1);
        conv3_tmaj<<<dim3(16, 16), 256, 0, stream>>>((const float*)h2t, w3, b3, noise, out);
    } else {
        float* h1 = (float*)d_ws;
        float* h2 = h1 + (size_t)16 * 512 * 2048;
        dim3 blk(256);
        conv_s2_kernel<<<dim3(2048 / BT, 512 / BCO, 16), blk, 0, stream>>>(
            x, w1, b1, h1, 512, 4096, 512, 2048, 1);
        conv_s2_kernel<<<dim3(1024 / BT, 512 / BCO, 16), blk, 0, stream>>>(
            h1, w2, b2, h2, 512, 2048, 512, 1024, 1);
        conv3_cmaj<<<dim3(16, 16), blk, 0, stream>>>(h2, w3, b3, noise, out);
    }
}